// Round 7
// baseline (171.724 us; speedup 1.0000x reference)
//
#include <hip/hip_runtime.h>

// 2-state HMM filtering scan. Block = 1 session (4 waves, 256 threads);
// lane owns 8 consecutive trials. Time-parallel via associative 2x2
// matrix-product scan: M_t = diag(e_t) @ T, state_t = normalize(s0 @ M..).
//
// This revision (single variable vs R6): ALL __shfl_up (ds_bpermute, a
// 64-lane crossbar op suspected to be throughput-limited) replaced by
// ping-pong LDS float4 exchange: ds_write_b128 -> s_waitcnt lgkmcnt(0) ->
// ds_read_b128 of slot lane-d. 16B/lane consecutive = conflict-free; all
// 4 matrix elements move in one DS op. No extra barriers (within-wave
// ordering via wave-wide lgkmcnt).

constexpr int NSESS   = 4096;
constexpr int NTRIALS = 2048;
constexpr int WAVES   = 4;                    // waves per block = per session
constexpr int THREADS = WAVES * 64;           // 256
constexpr int TPW     = NTRIALS / WAVES;      // 512 trials per wave
constexpr int LCH     = TPW / 64;             // 8 trials per lane

__device__ __forceinline__ float frcp(float x) {
    return __builtin_amdgcn_rcpf(x);
}

__global__ __launch_bounds__(THREADS) void hmm_kernel(
    const float* __restrict__ inp,     // (NSESS, NTRIALS, 3)
    const float* __restrict__ p_raw,
    const float* __restrict__ c_raw,
    float* __restrict__ out)           // (NSESS, NTRIALS, 2)
{
    __shared__ float4 xch[2][WAVES][64];   // ping-pong lane-exchange, 8 KB
    __shared__ float  lds_tot[WAVES][4];   // per-wave 2x2 totals

    const int t    = threadIdx.x;
    const int lane = t & 63;
    const int w    = t >> 6;
    const int sess = blockIdx.x;

    const float p = 1.0f / (1.0f + __expf(-p_raw[0]));
    const float c = 1.0f / (1.0f + __expf(-c_raw[0]));
    const float A = 0.5f * (1.0f + c), B = 0.5f * (1.0f - c);
    const float q = 0.5f * (1.0f + p), r = 0.5f * (1.0f - p);

    // ---- Phase 1: 6 independent float4 loads; 8 product steps, scalars only
    const float4* xv = reinterpret_cast<const float4*>(inp)
                     + (size_t)sess * (NTRIALS * 3 / 4)
                     + w * (TPW * 3 / 4) + lane * (LCH * 3 / 4);
    const float4 v0 = xv[0], v1 = xv[1], v2 = xv[2];
    const float4 v3 = xv[3], v4 = xv[4], v5 = xv[5];

    float p00 = 1.f, p01 = 0.f, p10 = 0.f, p11 = 1.f;
    float e0_0, e0_1, e0_2, e0_3, e0_4, e0_5, e0_6, e0_7;
    float e1_0, e1_1, e1_2, e1_3, e1_4, e1_5, e1_6, e1_7;

#define TRIAL(CL, CR, O, E0, E1)                                        \
    {                                                                   \
        float d0_ = (CL) * (O) + (CR) * (1.f - (O));                    \
        float d1_ = (CL) * (1.f - (O)) + (CR) * (O);                    \
        E0 = d0_ * A + d1_ * B;                                         \
        E1 = d0_ * B + d1_ * A;                                         \
        float m00_, m01_, m10_, m11_;                                   \
        if (E0 == 0.f && E1 == 0.f) { m00_ = q; m01_ = r; m10_ = r; m11_ = q; } \
        else { m00_ = E0 * q; m01_ = E0 * r; m10_ = E1 * r; m11_ = E1 * q; } \
        float n00_ = p00 * m00_ + p01 * m10_;                           \
        float n01_ = p00 * m01_ + p01 * m11_;                           \
        float n10_ = p10 * m00_ + p11 * m10_;                           \
        float n11_ = p10 * m01_ + p11 * m11_;                           \
        p00 = n00_; p01 = n01_; p10 = n10_; p11 = n11_;                 \
    }

    TRIAL(v0.x, v0.y, v0.z, e0_0, e1_0)
    TRIAL(v0.w, v1.x, v1.y, e0_1, e1_1)
    TRIAL(v1.z, v1.w, v2.x, e0_2, e1_2)
    TRIAL(v2.y, v2.z, v2.w, e0_3, e1_3)
    TRIAL(v3.x, v3.y, v3.z, e0_4, e1_4)
    TRIAL(v3.w, v4.x, v4.y, e0_5, e1_5)
    TRIAL(v4.z, v4.w, v5.x, e0_6, e1_6)
    TRIAL(v5.y, v5.z, v5.w, e0_7, e1_7)
#undef TRIAL

    // Normalize chunk product once
    {
        float inv = frcp(p00 + p01 + p10 + p11);
        p00 *= inv; p01 *= inv; p10 *= inv; p11 *= inv;
    }

    // ---- Phase 2: Kogge-Stone scan via LDS float4 exchange (no bpermute) ----
#define SCAN(D, BUF)                                                    \
    {                                                                   \
        xch[BUF][w][lane] = make_float4(p00, p01, p10, p11);            \
        asm volatile("s_waitcnt lgkmcnt(0)" ::: "memory");              \
        float4 a_ = xch[BUF][w][(lane - (D)) & 63];                     \
        if (lane >= (D)) {                                              \
            float n00_ = a_.x * p00 + a_.y * p10;                       \
            float n01_ = a_.x * p01 + a_.y * p11;                       \
            float n10_ = a_.z * p00 + a_.w * p10;                       \
            float n11_ = a_.z * p01 + a_.w * p11;                       \
            float inv_ = frcp(n00_ + n01_ + n10_ + n11_);               \
            p00 = n00_ * inv_; p01 = n01_ * inv_;                       \
            p10 = n10_ * inv_; p11 = n11_ * inv_;                       \
        }                                                               \
    }

    SCAN(1, 0) SCAN(2, 1) SCAN(4, 0) SCAN(8, 1) SCAN(16, 0) SCAN(32, 1)
#undef SCAN

    // Wave totals -> LDS (lane 63 holds the inclusive total)
    if (lane == 63) {
        lds_tot[w][0] = p00; lds_tot[w][1] = p01;
        lds_tot[w][2] = p10; lds_tot[w][3] = p11;
    }

    // Exclusive shift by 1 via LDS exchange (buffer 0; last scan used 1)
    xch[0][w][lane] = make_float4(p00, p01, p10, p11);
    asm volatile("s_waitcnt lgkmcnt(0)" ::: "memory");
    const float4 cprev = xch[0][w][(lane - 1) & 63];

    __syncthreads();   // publish lds_tot across waves

    // ---- Phase 3: start state = ([.5,.5] @ prefix-wave-totals) @ C_{lane-1}
    float s0 = 0.5f, s1 = 0.5f;
    for (int ww = 0; ww < w; ++ww) {                  // wave-uniform bound
        float t00 = lds_tot[ww][0], t01 = lds_tot[ww][1];
        float t10 = lds_tot[ww][2], t11 = lds_tot[ww][3];
        float n0 = s0 * t00 + s1 * t10;
        float n1 = s0 * t01 + s1 * t11;
        float inv = frcp(n0 + n1);
        s0 = n0 * inv; s1 = n1 * inv;
    }
    float u0 = s0, u1 = s1;
    if (lane > 0) {
        float n0 = s0 * cprev.x + s1 * cprev.z;
        float n1 = s0 * cprev.y + s1 * cprev.w;
        float inv = frcp(n0 + n1);
        u0 = n0 * inv; u1 = n1 * inv;
    }

    // ---- Phase 4: replay 8 trials, unnormalized recurrence; direct stores
#define REPLAY(E0, E1, O0, O1)                                          \
    {                                                                   \
        float w0_ = u0 * (E0), w1_ = u1 * (E1);                         \
        if (w0_ + w1_ == 0.f) { w0_ = u0; w1_ = u1; }                   \
        float n0_ = w0_ * q + w1_ * r;                                  \
        float n1_ = w0_ * r + w1_ * q;                                  \
        float inv_ = frcp(n0_ + n1_);    /* off recurrence chain */     \
        O0 = n0_ * inv_; O1 = n1_ * inv_;                               \
        u0 = n0_; u1 = n1_;                                             \
    }

    float4* yv = reinterpret_cast<float4*>(out)
               + (size_t)sess * (NTRIALS * 2 / 4) + w * (TPW * 2 / 4) + lane * 4;

    float o0a, o1a, o0b, o1b;
    REPLAY(e0_0, e1_0, o0a, o1a)
    REPLAY(e0_1, e1_1, o0b, o1b)
    yv[0] = make_float4(o0a, o1a, o0b, o1b);
    REPLAY(e0_2, e1_2, o0a, o1a)
    REPLAY(e0_3, e1_3, o0b, o1b)
    yv[1] = make_float4(o0a, o1a, o0b, o1b);
    REPLAY(e0_4, e1_4, o0a, o1a)
    REPLAY(e0_5, e1_5, o0b, o1b)
    yv[2] = make_float4(o0a, o1a, o0b, o1b);
    REPLAY(e0_6, e1_6, o0a, o1a)
    REPLAY(e0_7, e1_7, o0b, o1b)
    yv[3] = make_float4(o0a, o1a, o0b, o1b);
#undef REPLAY
}

extern "C" void kernel_launch(void* const* d_in, const int* in_sizes, int n_in,
                              void* d_out, int out_size, void* d_ws, size_t ws_size,
                              hipStream_t stream) {
    const float* inp   = (const float*)d_in[0];
    const float* p_raw = (const float*)d_in[1];
    const float* c_raw = (const float*)d_in[2];
    float* out = (float*)d_out;

    hmm_kernel<<<dim3(NSESS), dim3(THREADS), 0, stream>>>(inp, p_raw, c_raw, out);
}